// Round 1
// baseline (20802.751 us; speedup 1.0000x reference)
//
#include <hip/hip_runtime.h>
#include <math.h>

// ---------------- problem constants ----------------
#define B_   8
#define D_   768
#define H_   12
#define DH   64
#define L_   12
#define NTOK 785            // 1 + 28*28
#define NPAT 784
#define MTOT (B_ * NTOK)    // 6280
#define MPAT (B_ * NPAT)    // 6272
#define DFF  3072
#define EPS_ 1e-5f

// ---------------- GEMM: C[M,N] = A[M,K] @ W + bias (+gelu / +residual) ----
// BM=BN=128, BK=8, 256 threads, 8x8 micro-tile per thread.
// MODE: 0 = bias only, 1 = bias+gelu(exact), 2 = bias+residual
// WT:   false -> W is [K,N] row-major; true -> W is [N,K] row-major (B^T)
#define BM 128
#define BN 128
#define BK 8

__device__ __forceinline__ float gelu_exact(float x) {
    return 0.5f * x * (1.0f + erff(x * 0.70710678118654752f));
}

template <int MODE, bool WT>
__global__ __launch_bounds__(256) void gemm_kernel(
    const float* __restrict__ A, const float* __restrict__ W,
    const float* __restrict__ bias, const float* __restrict__ R,
    float* __restrict__ C, int M, int N, int K)
{
    __shared__ float As[BK][BM];
    __shared__ float Ws[BK][BN + 4];

    const int bm = blockIdx.y * BM;
    const int bn = blockIdx.x * BN;
    const int t  = threadIdx.x;
    const int tx = t & 15;   // 0..15 -> columns
    const int ty = t >> 4;   // 0..15 -> rows

    float acc[8][8];
#pragma unroll
    for (int i = 0; i < 8; i++)
#pragma unroll
        for (int j = 0; j < 8; j++) acc[i][j] = 0.0f;

    // A-tile load mapping: one float4 per thread
    const int ar = t >> 1;            // 0..127 (tile row)
    const int ak = (t & 1) * 4;       // 0 or 4 (k within tile)
    // W-tile load mapping
    const int wr = WT ? (t >> 1) : (t >> 5);        // WT: n-local; NT: k-local
    const int wc = WT ? ((t & 1) * 4) : ((t & 31) * 4);

    for (int kt = 0; kt < K; kt += BK) {
        // stage A (guard M)
        float4 av = {0.f, 0.f, 0.f, 0.f};
        const int grow = bm + ar;
        if (grow < M) av = *(const float4*)(A + (size_t)grow * K + kt + ak);
        As[ak + 0][ar] = av.x;
        As[ak + 1][ar] = av.y;
        As[ak + 2][ar] = av.z;
        As[ak + 3][ar] = av.w;
        // stage W (N is always a multiple of 128, K a multiple of 8)
        if (WT) {
            float4 wv = *(const float4*)(W + (size_t)(bn + wr) * K + kt + wc);
            Ws[wc + 0][wr] = wv.x;
            Ws[wc + 1][wr] = wv.y;
            Ws[wc + 2][wr] = wv.z;
            Ws[wc + 3][wr] = wv.w;
        } else {
            float4 wv = *(const float4*)(W + (size_t)(kt + wr) * N + bn + wc);
            Ws[wr][wc + 0] = wv.x;
            Ws[wr][wc + 1] = wv.y;
            Ws[wr][wc + 2] = wv.z;
            Ws[wr][wc + 3] = wv.w;
        }
        __syncthreads();

#pragma unroll
        for (int kk = 0; kk < BK; kk++) {
            float a[8], b[8];
#pragma unroll
            for (int i = 0; i < 8; i++) a[i] = As[kk][ty * 8 + i];
            // swizzled columns: two float4 chunks 64 apart -> <=2-way LDS aliasing
#pragma unroll
            for (int j = 0; j < 4; j++) b[j] = Ws[kk][tx * 4 + j];
#pragma unroll
            for (int j = 0; j < 4; j++) b[4 + j] = Ws[kk][64 + tx * 4 + j];
#pragma unroll
            for (int i = 0; i < 8; i++)
#pragma unroll
                for (int j = 0; j < 8; j++)
                    acc[i][j] = fmaf(a[i], b[j], acc[i][j]);
        }
        __syncthreads();
    }

    // epilogue
    const int c0 = bn + tx * 4;
    const int c1 = bn + 64 + tx * 4;
    const float4 bias0 = *(const float4*)(bias + c0);
    const float4 bias1 = *(const float4*)(bias + c1);
#pragma unroll
    for (int i = 0; i < 8; i++) {
        const int row = bm + ty * 8 + i;
        if (row >= M) continue;
        float4 r0 = make_float4(acc[i][0] + bias0.x, acc[i][1] + bias0.y,
                                acc[i][2] + bias0.z, acc[i][3] + bias0.w);
        float4 r1 = make_float4(acc[i][4] + bias1.x, acc[i][5] + bias1.y,
                                acc[i][6] + bias1.z, acc[i][7] + bias1.w);
        if (MODE == 1) {
            r0.x = gelu_exact(r0.x); r0.y = gelu_exact(r0.y);
            r0.z = gelu_exact(r0.z); r0.w = gelu_exact(r0.w);
            r1.x = gelu_exact(r1.x); r1.y = gelu_exact(r1.y);
            r1.z = gelu_exact(r1.z); r1.w = gelu_exact(r1.w);
        }
        if (MODE == 2) {
            const float4 q0 = *(const float4*)(R + (size_t)row * N + c0);
            const float4 q1 = *(const float4*)(R + (size_t)row * N + c1);
            r0.x += q0.x; r0.y += q0.y; r0.z += q0.z; r0.w += q0.w;
            r1.x += q1.x; r1.y += q1.y; r1.z += q1.z; r1.w += q1.w;
        }
        *(float4*)(C + (size_t)row * N + c0) = r0;
        *(float4*)(C + (size_t)row * N + c1) = r1;
    }
}

// ---------------- LayerNorm ----------------
// One 256-thread block per row of 768. row_stride_in selects tokens
// (768 for dense rows; NTOK*768 to pick token 0 of each batch for the final LN).
__device__ __forceinline__ float block_sum(float s, float* red) {
#pragma unroll
    for (int off = 32; off; off >>= 1) s += __shfl_down(s, off, 64);
    const int wid = threadIdx.x >> 6;
    if ((threadIdx.x & 63) == 0) red[wid] = s;
    __syncthreads();
    if (threadIdx.x == 0) red[0] = red[0] + red[1] + red[2] + red[3];
    __syncthreads();
    const float r = red[0];
    __syncthreads();
    return r;
}

__global__ __launch_bounds__(256) void ln_kernel(
    const float* __restrict__ X, const float* __restrict__ g,
    const float* __restrict__ b, float* __restrict__ Y, size_t row_stride_in)
{
    __shared__ float red[4];
    const int row = blockIdx.x;
    const int t = threadIdx.x;
    const float* x = X + (size_t)row * row_stride_in;

    float v0 = x[t], v1 = x[t + 256], v2 = x[t + 512];
    const float mean = block_sum(v0 + v1 + v2, red) * (1.0f / 768.0f);
    const float d0 = v0 - mean, d1 = v1 - mean, d2 = v2 - mean;
    const float var = block_sum(d0 * d0 + d1 * d1 + d2 * d2, red) * (1.0f / 768.0f);
    const float rs = rsqrtf(var + EPS_);

    float* y = Y + (size_t)row * 768;
    y[t]       = d0 * rs * g[t]       + b[t];
    y[t + 256] = d1 * rs * g[t + 256] + b[t + 256];
    y[t + 512] = d2 * rs * g[t + 512] + b[t + 512];
}

// ---------------- flash-style attention ----------------
// grid = (ceil(NTOK/32), B_*H_); 256 threads. Reads qkv [MTOT, 2304]
// (layout per token: [3, H, 64]); writes out [MTOT, 768] (= [.., h*64+d]).
#define QT 32
#define KT 32

__global__ __launch_bounds__(256) void attn_kernel(
    const float* __restrict__ qkv, float* __restrict__ out)
{
    __shared__ float Qs[QT][DH + 4];
    __shared__ float Ks[KT][DH + 4];
    __shared__ float Vs[KT][DH + 4];
    __shared__ float S[QT][KT + 1];
    __shared__ float m_s[QT], l_s[QT], al_s[QT];

    const int bh = blockIdx.y;
    const int b  = bh / H_;
    const int hh = bh % H_;
    const int q0 = blockIdx.x * QT;
    const int t  = threadIdx.x;
    const float scale = 0.125f;  // 64^-0.5

    // load Q tile (pre-scaled)
    for (int i = t; i < QT * 16; i += 256) {
        const int r = i >> 4, d4 = (i & 15) * 4;
        const int q = q0 + r;
        float4 v = {0.f, 0.f, 0.f, 0.f};
        if (q < NTOK)
            v = *(const float4*)(qkv + (size_t)(b * NTOK + q) * 2304 + hh * DH + d4);
        Qs[r][d4 + 0] = v.x * scale;
        Qs[r][d4 + 1] = v.y * scale;
        Qs[r][d4 + 2] = v.z * scale;
        Qs[r][d4 + 3] = v.w * scale;
    }
    if (t < QT) { m_s[t] = -1e30f; l_s[t] = 0.f; }

    float o[8] = {0.f, 0.f, 0.f, 0.f, 0.f, 0.f, 0.f, 0.f};
    const int r = t >> 3;  // 0..31 query row
    const int p = t & 7;   // 0..7  output-dim octet
    __syncthreads();

    for (int j0 = 0; j0 < NTOK; j0 += KT) {
        // stage K and V tiles
        for (int i = t; i < KT * 16; i += 256) {
            const int rr = i >> 4, d4 = (i & 15) * 4;
            const int j = j0 + rr;
            float4 kv = {0.f, 0.f, 0.f, 0.f}, vv = {0.f, 0.f, 0.f, 0.f};
            if (j < NTOK) {
                const float* base = qkv + (size_t)(b * NTOK + j) * 2304 + hh * DH + d4;
                kv = *(const float4*)(base + 768);
                vv = *(const float4*)(base + 1536);
            }
            Ks[rr][d4 + 0] = kv.x; Ks[rr][d4 + 1] = kv.y;
            Ks[rr][d4 + 2] = kv.z; Ks[rr][d4 + 3] = kv.w;
            Vs[rr][d4 + 0] = vv.x; Vs[rr][d4 + 1] = vv.y;
            Vs[rr][d4 + 2] = vv.z; Vs[rr][d4 + 3] = vv.w;
        }
        __syncthreads();

        // scores: each thread computes 4 of S[r][*]
        {
            const int jb = t & 7;
            float dots[4] = {0.f, 0.f, 0.f, 0.f};
            for (int d = 0; d < DH; d += 4) {
                const float4 qv = *(const float4*)(&Qs[r][d]);
#pragma unroll
                for (int jj = 0; jj < 4; jj++) {
                    const float4 kv = *(const float4*)(&Ks[jb + jj * 8][d]);
                    dots[jj] += qv.x * kv.x + qv.y * kv.y + qv.z * kv.z + qv.w * kv.w;
                }
            }
#pragma unroll
            for (int jj = 0; jj < 4; jj++) {
                const int j = jb + jj * 8;
                S[r][j] = (j0 + j < NTOK) ? dots[jj] : -1e30f;
            }
        }
        __syncthreads();

        // online softmax update (one thread per query row)
        if (t < QT) {
            const float mx = m_s[t];
            float tmax = -1e30f;
            for (int j = 0; j < KT; j++) tmax = fmaxf(tmax, S[t][j]);
            const float nm = fmaxf(mx, tmax);
            const float al = __expf(mx - nm);
            float sum = 0.f;
            for (int j = 0; j < KT; j++) {
                const float pj = __expf(S[t][j] - nm);
                S[t][j] = pj;
                sum += pj;
            }
            l_s[t] = l_s[t] * al + sum;
            m_s[t] = nm;
            al_s[t] = al;
        }
        __syncthreads();

        // O += P @ V (with rescale)
        {
            const float al = al_s[r];
#pragma unroll
            for (int c = 0; c < 8; c++) o[c] *= al;
            for (int j = 0; j < KT; j++) {
                const float pv = S[r][j];
                const float4 v0 = *(const float4*)(&Vs[j][p * 8]);
                const float4 v1 = *(const float4*)(&Vs[j][p * 8 + 4]);
                o[0] = fmaf(pv, v0.x, o[0]); o[1] = fmaf(pv, v0.y, o[1]);
                o[2] = fmaf(pv, v0.z, o[2]); o[3] = fmaf(pv, v0.w, o[3]);
                o[4] = fmaf(pv, v1.x, o[4]); o[5] = fmaf(pv, v1.y, o[5]);
                o[6] = fmaf(pv, v1.z, o[6]); o[7] = fmaf(pv, v1.w, o[7]);
            }
        }
        __syncthreads();
    }

    const int q = q0 + r;
    if (q < NTOK) {
        const float inv = 1.0f / l_s[r];
        float* dst = out + (size_t)(b * NTOK + q) * D_ + hh * DH + p * 8;
        *(float4*)(dst + 0) = make_float4(o[0] * inv, o[1] * inv, o[2] * inv, o[3] * inv);
        *(float4*)(dst + 4) = make_float4(o[4] * inv, o[5] * inv, o[6] * inv, o[7] * inv);
    }
}

// ---------------- im2col for the patch conv ----------------
// patches[b*784 + gy*28 + gx][c*256 + py*16 + px] = x[b, c, gy*16+py, gx*16+px]
__global__ __launch_bounds__(256) void im2col_kernel(
    const float* __restrict__ x, float* __restrict__ patches)
{
    const int idx = blockIdx.x * 256 + threadIdx.x;  // over MPAT*192 float4s
    if (idx >= MPAT * 192) return;
    const int prow = idx / 192;
    const int c4 = (idx % 192) * 4;
    const int bb = prow / NPAT;
    const int pp = prow % NPAT;
    const int gy = pp / 28, gx = pp % 28;
    const int c = c4 >> 8;
    const int rem = c4 & 255;
    const int py = rem >> 4, px = rem & 15;
    const float* src =
        x + (((size_t)(bb * 3 + c) * 448 + gy * 16 + py) * 448 + gx * 16 + px);
    *(float4*)(patches + (size_t)prow * 768 + c4) = *(const float4*)src;
}

// ---------------- assemble h = [cls|conv_out] + pos ----------------
__global__ __launch_bounds__(256) void assemble_kernel(
    const float* __restrict__ conv_out, const float* __restrict__ cls,
    const float* __restrict__ pos, float* __restrict__ h)
{
    const int idx = blockIdx.x * 256 + threadIdx.x;  // over MTOT*192 float4s
    if (idx >= MTOT * 192) return;
    const int row = idx / 192;
    const int d = (idx % 192) * 4;
    const int bb = row / NTOK, n = row % NTOK;
    const float4 pv = *(const float4*)(pos + (size_t)n * 768 + d);
    float4 v;
    if (n == 0) {
        const float4 cv = *(const float4*)(cls + d);
        v = make_float4(cv.x + pv.x, cv.y + pv.y, cv.z + pv.z, cv.w + pv.w);
    } else {
        const float4 co =
            *(const float4*)(conv_out + (size_t)(bb * NPAT + n - 1) * 768 + d);
        v = make_float4(co.x + pv.x, co.y + pv.y, co.z + pv.z, co.w + pv.w);
    }
    *(float4*)(h + (size_t)row * 768 + d) = v;
}

// ---------------- host orchestration ----------------
extern "C" void kernel_launch(void* const* d_in, const int* in_sizes, int n_in,
                              void* d_out, int out_size, void* d_ws, size_t ws_size,
                              hipStream_t stream)
{
    const float* x      = (const float*)d_in[0];
    const float* conv_w = (const float*)d_in[1];
    const float* conv_b = (const float*)d_in[2];
    const float* cls    = (const float*)d_in[3];
    const float* pos    = (const float*)d_in[4];
    const float* ln1_g  = (const float*)d_in[5];
    const float* ln1_b  = (const float*)d_in[6];
    const float* qkv_w  = (const float*)d_in[7];
    const float* qkv_b  = (const float*)d_in[8];
    const float* proj_w = (const float*)d_in[9];
    const float* proj_b = (const float*)d_in[10];
    const float* ln2_g  = (const float*)d_in[11];
    const float* ln2_b  = (const float*)d_in[12];
    const float* w1     = (const float*)d_in[13];
    const float* b1     = (const float*)d_in[14];
    const float* w2     = (const float*)d_in[15];
    const float* b2     = (const float*)d_in[16];
    const float* lnf_g  = (const float*)d_in[17];
    const float* lnf_b  = (const float*)d_in[18];
    float* out = (float*)d_out;

    // workspace layout (floats): h, y, qkv, attn, mid  (patches aliases mid)
    float* ws   = (float*)d_ws;
    float* h    = ws;                         // MTOT*768
    float* y    = h + (size_t)MTOT * 768;     // MTOT*768
    float* qkv  = y + (size_t)MTOT * 768;     // MTOT*2304
    float* attn = qkv + (size_t)MTOT * 2304;  // MTOT*768
    float* mid  = attn + (size_t)MTOT * 768;  // MTOT*3072
    float* patches = mid;                     // MPAT*768 (used only pre-loop)

    const dim3 blk(256);

    // PatchEmbed: im2col -> GEMM(A @ conv_w^T + conv_b) -> assemble with cls/pos
    im2col_kernel<<<(MPAT * 192 + 255) / 256, blk, 0, stream>>>(x, patches);
    gemm_kernel<0, true><<<dim3(768 / BN, (MPAT + BM - 1) / BM), blk, 0, stream>>>(
        patches, conv_w, conv_b, nullptr, y, MPAT, 768, 768);
    assemble_kernel<<<(MTOT * 192 + 255) / 256, blk, 0, stream>>>(y, cls, pos, h);

    const int gm = (MTOT + BM - 1) / BM;  // 50
    for (int l = 0; l < L_; l++) {
        ln_kernel<<<MTOT, blk, 0, stream>>>(h, ln1_g + l * 768, ln1_b + l * 768, y, 768);
        gemm_kernel<0, false><<<dim3(2304 / BN, gm), blk, 0, stream>>>(
            y, qkv_w + (size_t)l * 768 * 2304, qkv_b + l * 2304, nullptr, qkv,
            MTOT, 2304, 768);
        attn_kernel<<<dim3((NTOK + QT - 1) / QT, B_ * H_), blk, 0, stream>>>(qkv, attn);
        gemm_kernel<2, false><<<dim3(768 / BN, gm), blk, 0, stream>>>(
            attn, proj_w + (size_t)l * 768 * 768, proj_b + l * 768, h, h,
            MTOT, 768, 768);
        ln_kernel<<<MTOT, blk, 0, stream>>>(h, ln2_g + l * 768, ln2_b + l * 768, y, 768);
        gemm_kernel<1, false><<<dim3(DFF / BN, gm), blk, 0, stream>>>(
            y, w1 + (size_t)l * 768 * DFF, b1 + l * DFF, nullptr, mid,
            MTOT, DFF, 768);
        gemm_kernel<2, false><<<dim3(768 / BN, gm), blk, 0, stream>>>(
            mid, w2 + (size_t)l * DFF * 768, b2 + l * 768, h, h,
            MTOT, 768, DFF);
    }

    // final LN on token 0 of each batch -> out[8,768]
    ln_kernel<<<B_, blk, 0, stream>>>(h, lnf_g, lnf_b, out, (size_t)NTOK * 768);
}

// Round 2
// 12306.766 us; speedup vs baseline: 1.6904x; 1.6904x over previous
//
#include <hip/hip_runtime.h>
#include <math.h>

// ---------------- problem constants ----------------
#define B_   8
#define D_   768
#define H_   12
#define L_   12
#define NTOK 785            // 1 + 28*28
#define NPAT 784
#define MTOT (B_ * NTOK)    // 6280
#define MPAT (B_ * NPAT)    // 6272
#define MPAD 6400           // padded row count (multiple of 128)
#define DFF  3072
#define EPS_ 1e-5f

typedef unsigned short u16;
typedef unsigned int   u32;
typedef short s16x8 __attribute__((ext_vector_type(8)));
typedef float f32x4 __attribute__((ext_vector_type(4)));

__device__ __forceinline__ u16 f2b(float f) {
    u32 u = __float_as_uint(f);
    u += 0x7fffu + ((u >> 16) & 1u);   // RNE
    return (u16)(u >> 16);
}
__device__ __forceinline__ float b2f(u16 s) {
    return __uint_as_float(((u32)s) << 16);
}
__device__ __forceinline__ void gload_lds16(const void* g, void* l) {
    __builtin_amdgcn_global_load_lds(
        (const __attribute__((address_space(1))) void*)g,
        (__attribute__((address_space(3))) void*)l, 16, 0, 0);
}
__device__ __forceinline__ float gelu_exact(float x) {
    return 0.5f * x * (1.0f + erff(x * 0.70710678118654752f));
}

// ---------------- bf16 MFMA GEMM ----------------
// C[M,N] = A[M,K](bf16) @ W + bias, with WT[N,K](bf16) = W^T.
// 128x128 tile, BK=32, 256 threads (4 waves), each wave a 64x64 quadrant
// of 4x4 mfma_f32_16x16x32_bf16 tiles. A rows may be read up to the next
// multiple of 128 (buffers are padded to MPAD rows); stores guarded by M.
// MODE: 0 bias, 1 bias+gelu, 2 bias+residual(R fp32). OUTBF: 1 -> bf16 out.
template <int MODE, int OUTBF>
__global__ __launch_bounds__(256) void mfma_gemm(
    const u16* __restrict__ A, const u16* __restrict__ WT,
    const float* __restrict__ bias, const float* __restrict__ R,
    void* __restrict__ Cout, int M, int N, int K)
{
    __shared__ u16 As[128 * 32];
    __shared__ u16 Bs[128 * 32];

    const int bm = blockIdx.y * 128;
    const int bn = blockIdx.x * 128;
    const int t  = threadIdx.x;
    const int wv = t >> 6, ln = t & 63;
    const int wr = wv >> 1, wc = wv & 1;

    f32x4 acc[4][4];
    const f32x4 z4 = {0.f, 0.f, 0.f, 0.f};
#pragma unroll
    for (int i = 0; i < 4; i++)
#pragma unroll
        for (int j = 0; j < 4; j++) acc[i][j] = z4;

    const int lrow = ln & 15;
    const int kq   = (ln >> 4) * 8;

    for (int kt = 0; kt < K; kt += 32) {
        __syncthreads();   // previous iteration's ds_reads done
#pragma unroll
        for (int g = 0; g < 2; g++) {
            const int c = wv * 64 + g * 256 + ln;       // 16B chunk id, 0..511
            const int r = c >> 2, kc = (c & 3) * 8;
            u16* ldsA = As + (wv * 64 + g * 256) * 8;   // wave-uniform base
            u16* ldsB = Bs + (wv * 64 + g * 256) * 8;
            gload_lds16(A  + (size_t)(bm + r) * K + kt + kc, ldsA);
            gload_lds16(WT + (size_t)(bn + r) * K + kt + kc, ldsB);
        }
        __syncthreads();   // drains vmcnt

        s16x8 af[4], bf[4];
#pragma unroll
        for (int i = 0; i < 4; i++)
            af[i] = *(const s16x8*)(As + (wr * 64 + i * 16 + lrow) * 32 + kq);
#pragma unroll
        for (int j = 0; j < 4; j++)
            bf[j] = *(const s16x8*)(Bs + (wc * 64 + j * 16 + lrow) * 32 + kq);
#pragma unroll
        for (int i = 0; i < 4; i++)
#pragma unroll
            for (int j = 0; j < 4; j++)
                acc[i][j] = __builtin_amdgcn_mfma_f32_16x16x32_bf16(
                    af[i], bf[j], acc[i][j], 0, 0, 0);
    }

    // epilogue: D row = (ln>>4)*4 + reg, col = ln&15 (per 16x16 tile)
    const int col_l = ln & 15;
    const int rq    = (ln >> 4) * 4;
#pragma unroll
    for (int j = 0; j < 4; j++) {
        const int col = bn + wc * 64 + j * 16 + col_l;
        const float bj = bias[col];
#pragma unroll
        for (int i = 0; i < 4; i++) {
            const int row0 = bm + wr * 64 + i * 16 + rq;
#pragma unroll
            for (int rg = 0; rg < 4; rg++) {
                const int row = row0 + rg;
                if (row >= M) continue;
                float v = acc[i][j][rg] + bj;
                if (MODE == 1) v = gelu_exact(v);
                if (MODE == 2) v += R[(size_t)row * N + col];
                if (OUTBF) ((u16*)Cout)[(size_t)row * N + col] = f2b(v);
                else       ((float*)Cout)[(size_t)row * N + col] = v;
            }
        }
    }
}

// ---------------- weight convert + transpose: W[K,N] f32 -> WT[N,K] bf16 ----
__global__ __launch_bounds__(256) void wt_kernel(
    const float* __restrict__ W, u16* __restrict__ WT, int K, int N)
{
    __shared__ float tile[32][33];
    const int n0 = blockIdx.x * 32, k0 = blockIdx.y * 32;
    const int r = threadIdx.x >> 3, c4 = (threadIdx.x & 7) * 4;
    const float4 v = *(const float4*)(W + (size_t)(k0 + r) * N + n0 + c4);
    tile[r][c4 + 0] = v.x; tile[r][c4 + 1] = v.y;
    tile[r][c4 + 2] = v.z; tile[r][c4 + 3] = v.w;
    __syncthreads();
    ushort4 o = make_ushort4(f2b(tile[c4 + 0][r]), f2b(tile[c4 + 1][r]),
                             f2b(tile[c4 + 2][r]), f2b(tile[c4 + 3][r]));
    *(ushort4*)(WT + (size_t)(n0 + r) * K + k0 + c4) = o;
}

// ---------------- flat f32 -> bf16 convert (conv_w is already [N,K]) ------
__global__ __launch_bounds__(256) void flatcvt_kernel(
    const float* __restrict__ in, u16* __restrict__ out, int n4)
{
    const int i = blockIdx.x * 256 + threadIdx.x;
    if (i >= n4) return;
    const float4 v = ((const float4*)in)[i];
    ((ushort4*)out)[i] = make_ushort4(f2b(v.x), f2b(v.y), f2b(v.z), f2b(v.w));
}

// ---------------- LayerNorm (fp32 in, bf16 or fp32 out) ----------------
__device__ __forceinline__ float block_sum(float s, float* red) {
#pragma unroll
    for (int off = 32; off; off >>= 1) s += __shfl_down(s, off, 64);
    const int wid = threadIdx.x >> 6;
    if ((threadIdx.x & 63) == 0) red[wid] = s;
    __syncthreads();
    if (threadIdx.x == 0) red[0] = red[0] + red[1] + red[2] + red[3];
    __syncthreads();
    const float r = red[0];
    __syncthreads();
    return r;
}

template <int OUTBF>
__global__ __launch_bounds__(256) void ln_kernel(
    const float* __restrict__ X, const float* __restrict__ g,
    const float* __restrict__ b, void* __restrict__ Y, size_t row_stride_in)
{
    __shared__ float red[4];
    const int row = blockIdx.x;
    const int t = threadIdx.x;
    const float* x = X + (size_t)row * row_stride_in;

    const float v0 = x[t], v1 = x[t + 256], v2 = x[t + 512];
    const float mean = block_sum(v0 + v1 + v2, red) * (1.0f / 768.0f);
    const float d0 = v0 - mean, d1 = v1 - mean, d2 = v2 - mean;
    const float var = block_sum(d0 * d0 + d1 * d1 + d2 * d2, red) * (1.0f / 768.0f);
    const float rs = rsqrtf(var + EPS_);

    const float o0 = d0 * rs * g[t] + b[t];
    const float o1 = d1 * rs * g[t + 256] + b[t + 256];
    const float o2 = d2 * rs * g[t + 512] + b[t + 512];
    if (OUTBF) {
        u16* y = (u16*)Y + (size_t)row * 768;
        y[t] = f2b(o0); y[t + 256] = f2b(o1); y[t + 512] = f2b(o2);
    } else {
        float* y = (float*)Y + (size_t)row * 768;
        y[t] = o0; y[t + 256] = o1; y[t + 512] = o2;
    }
}

// ---------------- flash attention (bf16 IO, fp32 VALU compute) ----------
// grid (ceil(NTOK/32), B_*H_), 256 threads. Thread (r = t>>3, g = t&7):
// scores for q-row r, k-cols g*4..g*4+3; online-softmax state in registers,
// 8-lane shuffle reductions; output cols g*8..g*8+7.
__global__ __launch_bounds__(256) void attn_kernel(
    const u16* __restrict__ qkv, u16* __restrict__ out)
{
    __shared__ float Qs[32][65];
    __shared__ float Ks[32][65];
    __shared__ float Vs[32][65];
    __shared__ float S[32][33];

    const int bh = blockIdx.y;
    const int b  = bh / H_;
    const int hh = bh % H_;
    const int q0 = blockIdx.x * 32;
    const int t  = threadIdx.x;
    const int r  = t >> 3, g = t & 7;

    // load Q tile (pre-scaled by 1/8): one 8-elem chunk per thread
    {
        const int d8 = g * 8;
        const int q = q0 + r;
        if (q < NTOK) {
            const u16* src = qkv + (size_t)(b * NTOK + q) * 2304 + hh * 64 + d8;
#pragma unroll
            for (int e = 0; e < 8; e++) Qs[r][d8 + e] = b2f(src[e]) * 0.125f;
        } else {
#pragma unroll
            for (int e = 0; e < 8; e++) Qs[r][d8 + e] = 0.f;
        }
    }
    float m_r = -1e30f, l_r = 0.f;
    float o[8] = {0.f, 0.f, 0.f, 0.f, 0.f, 0.f, 0.f, 0.f};
    __syncthreads();

    for (int j0 = 0; j0 < NTOK; j0 += 32) {
        // stage K/V tiles
        {
            const int d8 = g * 8;
            const int j = j0 + r;
            if (j < NTOK) {
                const u16* base = qkv + (size_t)(b * NTOK + j) * 2304 + hh * 64 + d8;
#pragma unroll
                for (int e = 0; e < 8; e++) Ks[r][d8 + e] = b2f(base[768 + e]);
#pragma unroll
                for (int e = 0; e < 8; e++) Vs[r][d8 + e] = b2f(base[1536 + e]);
            } else {
#pragma unroll
                for (int e = 0; e < 8; e++) { Ks[r][d8 + e] = 0.f; Vs[r][d8 + e] = 0.f; }
            }
        }
        __syncthreads();

        // scores: 4 consecutive k-cols per thread
        const int jb = g * 4;
        float dots[4] = {0.f, 0.f, 0.f, 0.f};
        for (int d = 0; d < 64; d += 4) {
            const float4 qv = *(const float4*)(&Qs[r][d]);
#pragma unroll
            for (int jj = 0; jj < 4; jj++) {
                const float4 kv = *(const float4*)(&Ks[jb + jj][d]);
                dots[jj] += qv.x * kv.x + qv.y * kv.y + qv.z * kv.z + qv.w * kv.w;
            }
        }
#pragma unroll
        for (int jj = 0; jj < 4; jj++)
            if (j0 + jb + jj >= NTOK) dots[jj] = -1e30f;

        // online softmax (8-lane group reduction, state in registers)
        float tmax = fmaxf(fmaxf(dots[0], dots[1]), fmaxf(dots[2], dots[3]));
        tmax = fmaxf(tmax, __shfl_xor(tmax, 1, 64));
        tmax = fmaxf(tmax, __shfl_xor(tmax, 2, 64));
        tmax = fmaxf(tmax, __shfl_xor(tmax, 4, 64));
        const float nm = fmaxf(m_r, tmax);
        const float alpha = __expf(m_r - nm);
        float psum = 0.f;
#pragma unroll
        for (int jj = 0; jj < 4; jj++) {
            const float p = __expf(dots[jj] - nm);
            S[r][jb + jj] = p;
            psum += p;
        }
        psum += __shfl_xor(psum, 1, 64);
        psum += __shfl_xor(psum, 2, 64);
        psum += __shfl_xor(psum, 4, 64);
        l_r = l_r * alpha + psum;
        m_r = nm;
        __syncthreads();

        // O += P @ V (with rescale)
#pragma unroll
        for (int c = 0; c < 8; c++) o[c] *= alpha;
        for (int j = 0; j < 32; j++) {
            const float pv = S[r][j];
            const float4 v0 = *(const float4*)(&Vs[j][g * 8]);
            const float4 v1 = *(const float4*)(&Vs[j][g * 8 + 4]);
            o[0] = fmaf(pv, v0.x, o[0]); o[1] = fmaf(pv, v0.y, o[1]);
            o[2] = fmaf(pv, v0.z, o[2]); o[3] = fmaf(pv, v0.w, o[3]);
            o[4] = fmaf(pv, v1.x, o[4]); o[5] = fmaf(pv, v1.y, o[5]);
            o[6] = fmaf(pv, v1.z, o[6]); o[7] = fmaf(pv, v1.w, o[7]);
        }
        __syncthreads();
    }

    const int q = q0 + r;
    if (q < NTOK) {
        const float inv = 1.0f / l_r;
        u16* dst = out + (size_t)(b * NTOK + q) * D_ + hh * 64 + g * 8;
        uint4 w4;
        w4.x = (u32)f2b(o[0] * inv) | ((u32)f2b(o[1] * inv) << 16);
        w4.y = (u32)f2b(o[2] * inv) | ((u32)f2b(o[3] * inv) << 16);
        w4.z = (u32)f2b(o[4] * inv) | ((u32)f2b(o[5] * inv) << 16);
        w4.w = (u32)f2b(o[6] * inv) | ((u32)f2b(o[7] * inv) << 16);
        *(uint4*)dst = w4;
    }
}

// ---------------- im2col (fp32 -> bf16 patches) ----------------
__global__ __launch_bounds__(256) void im2col_kernel(
    const float* __restrict__ x, u16* __restrict__ patches)
{
    const int idx = blockIdx.x * 256 + threadIdx.x;  // over MPAT*96 8-chunks
    if (idx >= MPAT * 96) return;
    const int prow = idx / 96;
    const int c8 = (idx % 96) * 8;
    const int bb = prow / NPAT;
    const int pp = prow % NPAT;
    const int gy = pp / 28, gx = pp % 28;
    const int c = c8 >> 8;
    const int rem = c8 & 255;
    const int py = rem >> 4, px = rem & 15;
    const float* src =
        x + (((size_t)(bb * 3 + c) * 448 + gy * 16 + py) * 448 + gx * 16 + px);
    const float4 a = *(const float4*)src;
    const float4 bq = *(const float4*)(src + 4);
    u16* dst = patches + (size_t)prow * 768 + c8;
    uint4 w4;
    w4.x = (u32)f2b(a.x) | ((u32)f2b(a.y) << 16);
    w4.y = (u32)f2b(a.z) | ((u32)f2b(a.w) << 16);
    w4.z = (u32)f2b(bq.x) | ((u32)f2b(bq.y) << 16);
    w4.w = (u32)f2b(bq.z) | ((u32)f2b(bq.w) << 16);
    *(uint4*)dst = w4;
}

// ---------------- assemble h = [cls|conv_out] + pos (fp32) ----------------
__global__ __launch_bounds__(256) void assemble_kernel(
    const float* __restrict__ conv_out, const float* __restrict__ cls,
    const float* __restrict__ pos, float* __restrict__ h)
{
    const int idx = blockIdx.x * 256 + threadIdx.x;  // over MTOT*192 float4s
    if (idx >= MTOT * 192) return;
    const int row = idx / 192;
    const int d = (idx % 192) * 4;
    const int bb = row / NTOK, n = row % NTOK;
    const float4 pv = *(const float4*)(pos + (size_t)n * 768 + d);
    float4 v;
    if (n == 0) {
        const float4 cv = *(const float4*)(cls + d);
        v = make_float4(cv.x + pv.x, cv.y + pv.y, cv.z + pv.z, cv.w + pv.w);
    } else {
        const float4 co =
            *(const float4*)(conv_out + (size_t)(bb * NPAT + n - 1) * 768 + d);
        v = make_float4(co.x + pv.x, co.y + pv.y, co.z + pv.z, co.w + pv.w);
    }
    *(float4*)(h + (size_t)row * 768 + d) = v;
}

// ---------------- host orchestration ----------------
extern "C" void kernel_launch(void* const* d_in, const int* in_sizes, int n_in,
                              void* d_out, int out_size, void* d_ws, size_t ws_size,
                              hipStream_t stream)
{
    const float* x      = (const float*)d_in[0];
    const float* conv_w = (const float*)d_in[1];
    const float* conv_b = (const float*)d_in[2];
    const float* cls    = (const float*)d_in[3];
    const float* pos    = (const float*)d_in[4];
    const float* ln1_g  = (const float*)d_in[5];
    const float* ln1_b  = (const float*)d_in[6];
    const float* qkv_w  = (const float*)d_in[7];
    const float* qkv_b  = (const float*)d_in[8];
    const float* proj_w = (const float*)d_in[9];
    const float* proj_b = (const float*)d_in[10];
    const float* ln2_g  = (const float*)d_in[11];
    const float* ln2_b  = (const float*)d_in[12];
    const float* w1     = (const float*)d_in[13];
    const float* b1     = (const float*)d_in[14];
    const float* w2     = (const float*)d_in[15];
    const float* b2     = (const float*)d_in[16];
    const float* lnf_g  = (const float*)d_in[17];
    const float* lnf_b  = (const float*)d_in[18];
    float* out = (float*)d_out;

    // workspace layout (256B aligned). ~124 MB total (fits the >=193MB ws).
    char* p = (char*)d_ws;
    auto alloc = [&](size_t bytes) {
        char* r = p;
        p += (bytes + 255) & ~(size_t)255;
        return r;
    };
    float* h    = (float*)alloc((size_t)MPAD * 768 * 4);
    u16*  y     = (u16*)alloc((size_t)MPAD * 768 * 2);
    u16*  qkv   = (u16*)alloc((size_t)MPAD * 2304 * 2);
    u16*  attn  = (u16*)alloc((size_t)MPAD * 768 * 2);
    u16*  mid   = (u16*)alloc((size_t)MPAD * 3072 * 2);
    u16*  wq    = (u16*)alloc((size_t)2304 * 768 * 2);
    u16*  wp    = (u16*)alloc((size_t)768 * 768 * 2);
    u16*  w1t   = (u16*)alloc((size_t)3072 * 768 * 2);
    u16*  w2t   = (u16*)alloc((size_t)768 * 3072 * 2);
    u16*  wcv   = (u16*)alloc((size_t)768 * 768 * 2);
    (void)alloc(4096);  // slack
    u16*   patches = mid;       // pre-loop alias
    float* cbuf    = (float*)qkv;  // pre-loop alias (fp32 conv out)

    const dim3 blk(256);

    // PatchEmbed: convert conv_w (already [N,K]), im2col, GEMM, assemble
    flatcvt_kernel<<<(768 * 768 / 4 + 255) / 256, blk, 0, stream>>>(conv_w, wcv,
                                                                    768 * 768 / 4);
    im2col_kernel<<<(MPAT * 96 + 255) / 256, blk, 0, stream>>>(x, patches);
    mfma_gemm<0, 0><<<dim3(6, MPAT / 128), blk, 0, stream>>>(
        patches, wcv, conv_b, nullptr, cbuf, MPAT, 768, 768);
    assemble_kernel<<<(MTOT * 192 + 255) / 256, blk, 0, stream>>>(cbuf, cls, pos, h);

    for (int l = 0; l < L_; l++) {
        // per-layer weight convert+transpose to bf16 [N,K]
        wt_kernel<<<dim3(2304 / 32, 768 / 32), blk, 0, stream>>>(
            qkv_w + (size_t)l * 768 * 2304, wq, 768, 2304);
        wt_kernel<<<dim3(768 / 32, 768 / 32), blk, 0, stream>>>(
            proj_w + (size_t)l * 768 * 768, wp, 768, 768);
        wt_kernel<<<dim3(3072 / 32, 768 / 32), blk, 0, stream>>>(
            w1 + (size_t)l * 768 * 3072, w1t, 768, 3072);
        wt_kernel<<<dim3(768 / 32, 3072 / 32), blk, 0, stream>>>(
            w2 + (size_t)l * 3072 * 768, w2t, 3072, 768);

        ln_kernel<1><<<MTOT, blk, 0, stream>>>(h, ln1_g + l * 768, ln1_b + l * 768,
                                               y, 768);
        mfma_gemm<0, 1><<<dim3(18, 50), blk, 0, stream>>>(
            y, wq, qkv_b + l * 2304, nullptr, qkv, MTOT, 2304, 768);
        attn_kernel<<<dim3(25, B_ * H_), blk, 0, stream>>>(qkv, attn);
        mfma_gemm<2, 0><<<dim3(6, 50), blk, 0, stream>>>(
            attn, wp, proj_b + l * 768, h, h, MTOT, 768, 768);
        ln_kernel<1><<<MTOT, blk, 0, stream>>>(h, ln2_g + l * 768, ln2_b + l * 768,
                                               y, 768);
        mfma_gemm<1, 1><<<dim3(24, 50), blk, 0, stream>>>(
            y, w1t, b1 + l * DFF, nullptr, mid, MTOT, DFF, 768);
        mfma_gemm<2, 0><<<dim3(6, 50), blk, 0, stream>>>(
            mid, w2t, b2 + l * 768, h, h, MTOT, 768, DFF);
    }

    // final LN on token 0 of each batch -> out[8,768] (fp32)
    ln_kernel<0><<<B_, blk, 0, stream>>>(h, lnf_g, lnf_b, out, (size_t)NTOK * 768);
}

// Round 3
// 4810.408 us; speedup vs baseline: 4.3245x; 2.5584x over previous
//
#include <hip/hip_runtime.h>
#include <math.h>

// ---------------- problem constants ----------------
#define B_   8
#define D_   768
#define H_   12
#define L_   12
#define NTOK 785            // 1 + 28*28
#define NPAT 784
#define MTOT (B_ * NTOK)    // 6280
#define MPAT (B_ * NPAT)    // 6272
#define MPAD 6400           // padded row count (multiple of 128)
#define DFF  3072
#define EPS_ 1e-5f

typedef unsigned short u16;
typedef unsigned int   u32;
typedef short s16x8 __attribute__((ext_vector_type(8)));
typedef float f32x4 __attribute__((ext_vector_type(4)));

__device__ __forceinline__ u16 f2b(float f) {
    u32 u = __float_as_uint(f);
    u += 0x7fffu + ((u >> 16) & 1u);   // RNE
    return (u16)(u >> 16);
}
__device__ __forceinline__ float b2f(u16 s) {
    return __uint_as_float(((u32)s) << 16);
}
__device__ __forceinline__ void gload_lds16(const void* g, void* l) {
    __builtin_amdgcn_global_load_lds(
        (const __attribute__((address_space(1))) void*)g,
        (__attribute__((address_space(3))) void*)l, 16, 0, 0);
}
__device__ __forceinline__ float gelu_exact(float x) {
    return 0.5f * x * (1.0f + erff(x * 0.70710678118654752f));
}

// ---------------- bf16 MFMA GEMM ----------------
// C[M,N] = A[M,K](bf16) @ W + bias, with WT[N,K](bf16) = W^T.
// 128x128 tile, BK=32, 256 threads (4 waves), each wave a 64x64 quadrant
// of 4x4 mfma_f32_16x16x32_bf16 tiles.
// MODE: 0 bias, 1 bias+gelu, 2 bias+residual(R fp32). OUTBF: 1 -> bf16 out.
template <int MODE, int OUTBF>
__global__ __launch_bounds__(256) void mfma_gemm(
    const u16* __restrict__ A, const u16* __restrict__ WT,
    const float* __restrict__ bias, const float* __restrict__ R,
    void* __restrict__ Cout, int M, int N, int K)
{
    __shared__ u16 As[128 * 32];
    __shared__ u16 Bs[128 * 32];

    const int bm = blockIdx.y * 128;
    const int bn = blockIdx.x * 128;
    const int t  = threadIdx.x;
    const int wv = t >> 6, ln = t & 63;
    const int wr = wv >> 1, wc = wv & 1;

    f32x4 acc[4][4];
    const f32x4 z4 = {0.f, 0.f, 0.f, 0.f};
#pragma unroll
    for (int i = 0; i < 4; i++)
#pragma unroll
        for (int j = 0; j < 4; j++) acc[i][j] = z4;

    const int lrow = ln & 15;
    const int kq   = (ln >> 4) * 8;

    for (int kt = 0; kt < K; kt += 32) {
        __syncthreads();
#pragma unroll
        for (int g = 0; g < 2; g++) {
            const int c = wv * 64 + g * 256 + ln;       // 16B chunk id, 0..511
            const int r = c >> 2, kc = (c & 3) * 8;
            u16* ldsA = As + (wv * 64 + g * 256) * 8;   // wave-uniform base
            u16* ldsB = Bs + (wv * 64 + g * 256) * 8;
            gload_lds16(A  + (size_t)(bm + r) * K + kt + kc, ldsA);
            gload_lds16(WT + (size_t)(bn + r) * K + kt + kc, ldsB);
        }
        __syncthreads();

        s16x8 af[4], bf[4];
#pragma unroll
        for (int i = 0; i < 4; i++)
            af[i] = *(const s16x8*)(As + (wr * 64 + i * 16 + lrow) * 32 + kq);
#pragma unroll
        for (int j = 0; j < 4; j++)
            bf[j] = *(const s16x8*)(Bs + (wc * 64 + j * 16 + lrow) * 32 + kq);
#pragma unroll
        for (int i = 0; i < 4; i++)
#pragma unroll
            for (int j = 0; j < 4; j++)
                acc[i][j] = __builtin_amdgcn_mfma_f32_16x16x32_bf16(
                    af[i], bf[j], acc[i][j], 0, 0, 0);
    }

    const int col_l = ln & 15;
    const int rq    = (ln >> 4) * 4;
#pragma unroll
    for (int j = 0; j < 4; j++) {
        const int col = bn + wc * 64 + j * 16 + col_l;
        const float bj = bias[col];
#pragma unroll
        for (int i = 0; i < 4; i++) {
            const int row0 = bm + wr * 64 + i * 16 + rq;
#pragma unroll
            for (int rg = 0; rg < 4; rg++) {
                const int row = row0 + rg;
                if (row >= M) continue;
                float v = acc[i][j][rg] + bj;
                if (MODE == 1) v = gelu_exact(v);
                if (MODE == 2) v += R[(size_t)row * N + col];
                if (OUTBF) ((u16*)Cout)[(size_t)row * N + col] = f2b(v);
                else       ((float*)Cout)[(size_t)row * N + col] = v;
            }
        }
    }
}

// ---------------- weight convert + transpose: W[K,N] f32 -> WT[N,K] bf16 ----
__global__ __launch_bounds__(256) void wt_kernel(
    const float* __restrict__ W, u16* __restrict__ WT, int K, int N)
{
    __shared__ float tile[32][33];
    const int n0 = blockIdx.x * 32, k0 = blockIdx.y * 32;
    const int r = threadIdx.x >> 3, c4 = (threadIdx.x & 7) * 4;
    const float4 v = *(const float4*)(W + (size_t)(k0 + r) * N + n0 + c4);
    tile[r][c4 + 0] = v.x; tile[r][c4 + 1] = v.y;
    tile[r][c4 + 2] = v.z; tile[r][c4 + 3] = v.w;
    __syncthreads();
    ushort4 o = make_ushort4(f2b(tile[c4 + 0][r]), f2b(tile[c4 + 1][r]),
                             f2b(tile[c4 + 2][r]), f2b(tile[c4 + 3][r]));
    *(ushort4*)(WT + (size_t)(n0 + r) * K + k0 + c4) = o;
}

// ---------------- flat f32 -> bf16 convert ----------------
__global__ __launch_bounds__(256) void flatcvt_kernel(
    const float* __restrict__ in, u16* __restrict__ out, int n4)
{
    const int i = blockIdx.x * 256 + threadIdx.x;
    if (i >= n4) return;
    const float4 v = ((const float4*)in)[i];
    ((ushort4*)out)[i] = make_ushort4(f2b(v.x), f2b(v.y), f2b(v.z), f2b(v.w));
}

// ---------------- LayerNorm (fp32 in, bf16 or fp32 out) ----------------
__device__ __forceinline__ float block_sum(float s, float* red) {
#pragma unroll
    for (int off = 32; off; off >>= 1) s += __shfl_down(s, off, 64);
    const int wid = threadIdx.x >> 6;
    if ((threadIdx.x & 63) == 0) red[wid] = s;
    __syncthreads();
    if (threadIdx.x == 0) red[0] = red[0] + red[1] + red[2] + red[3];
    __syncthreads();
    const float r = red[0];
    __syncthreads();
    return r;
}

template <int OUTBF>
__global__ __launch_bounds__(256) void ln_kernel(
    const float* __restrict__ X, const float* __restrict__ g,
    const float* __restrict__ b, void* __restrict__ Y, size_t row_stride_in)
{
    __shared__ float red[4];
    const int row = blockIdx.x;
    const int t = threadIdx.x;
    const float* x = X + (size_t)row * row_stride_in;

    const float v0 = x[t], v1 = x[t + 256], v2 = x[t + 512];
    const float mean = block_sum(v0 + v1 + v2, red) * (1.0f / 768.0f);
    const float d0 = v0 - mean, d1 = v1 - mean, d2 = v2 - mean;
    const float var = block_sum(d0 * d0 + d1 * d1 + d2 * d2, red) * (1.0f / 768.0f);
    const float rs = rsqrtf(var + EPS_);

    const float o0 = d0 * rs * g[t] + b[t];
    const float o1 = d1 * rs * g[t + 256] + b[t + 256];
    const float o2 = d2 * rs * g[t + 512] + b[t + 512];
    if (OUTBF) {
        u16* y = (u16*)Y + (size_t)row * 768;
        y[t] = f2b(o0); y[t + 256] = f2b(o1); y[t + 512] = f2b(o2);
    } else {
        float* y = (float*)Y + (size_t)row * 768;
        y[t] = o0; y[t + 256] = o1; y[t + 512] = o2;
    }
}

// ---------------- MFMA flash attention ----------------
// Block: one (b,h), 128 q-rows; 4 waves x 32 q-rows (2 row-tiles of 16).
// K-tiles of 64 tokens. QK^T and PV via mfma_f32_16x16x32_bf16 (NT form).
// Softmax in C-fragment space: per-lane partials over jt + 4 xor-shuffles
// across the 16-lane column group. P goes C-layout -> LDS (bf16, stride 72)
// -> A-layout fragments. Vt staged transposed (2-way-free b16 writes).
#define AQB  128
#define AKT  64
#define KSTR 72   // u16 row stride: 144B rows -> b128 frag reads at bank floor

__global__ __launch_bounds__(256) void attn_kernel(
    const u16* __restrict__ qkv, u16* __restrict__ out)
{
    __shared__ u16 Ks[AKT * KSTR];
    __shared__ u16 Vt[64 * KSTR];
    __shared__ u16 Ps[4 * 32 * KSTR];

    const int bh = blockIdx.y;
    const int b  = bh / H_, hh = bh % H_;
    const int q0 = blockIdx.x * AQB;
    const int t  = threadIdx.x;
    const int w  = t >> 6, ln = t & 63;
    const int lrow = ln & 15, quad = ln >> 4;
    const size_t tokbase = (size_t)b * NTOK;

    // Q A-fragments (held in registers for the whole kernel)
    s16x8 aq[2][2];
#pragma unroll
    for (int rowt = 0; rowt < 2; rowt++) {
        int qr = q0 + w * 32 + rowt * 16 + lrow;
        if (qr > NTOK - 1) qr = NTOK - 1;
        const u16* qp = qkv + (tokbase + qr) * 2304 + hh * 64 + quad * 8;
        aq[rowt][0] = *(const s16x8*)(qp);
        aq[rowt][1] = *(const s16x8*)(qp + 32);
    }

    f32x4 acc_o[2][4];
    const f32x4 z4 = {0.f, 0.f, 0.f, 0.f};
#pragma unroll
    for (int i = 0; i < 2; i++)
#pragma unroll
        for (int j = 0; j < 4; j++) acc_o[i][j] = z4;
    float m_r[2][4], l_r[2][4];
#pragma unroll
    for (int i = 0; i < 2; i++)
#pragma unroll
        for (int j = 0; j < 4; j++) { m_r[i][j] = -1e30f; l_r[i][j] = 0.f; }

    for (int j0 = 0; j0 < NTOK; j0 += AKT) {
        __syncthreads();   // previous tile's reads complete
        // stage K [64 tok][64 d], padded rows
#pragma unroll
        for (int g = 0; g < 2; g++) {
            const int c = g * 256 + t;
            const int j = c >> 3, dc = c & 7;
            int jj = j0 + j; if (jj > NTOK - 1) jj = NTOK - 1;
            const s16x8 kv = *(const s16x8*)(
                qkv + (tokbase + jj) * 2304 + 768 + hh * 64 + dc * 8);
            *(s16x8*)(Ks + j * KSTR + dc * 8) = kv;
        }
        // stage V transposed: Vt[d][j]
#pragma unroll
        for (int g = 0; g < 2; g++) {
            const int c = g * 256 + t;
            const int j = c & 63, dc = c >> 6;
            int jj = j0 + j; if (jj > NTOK - 1) jj = NTOK - 1;
            const s16x8 vv = *(const s16x8*)(
                qkv + (tokbase + jj) * 2304 + 1536 + hh * 64 + dc * 8);
#pragma unroll
            for (int e = 0; e < 8; e++)
                Vt[(dc * 8 + e) * KSTR + j] = (u16)((const short*)&vv)[e];
        }
        __syncthreads();

        // S = Q K^T
        f32x4 acc_s[2][4];
#pragma unroll
        for (int i = 0; i < 2; i++)
#pragma unroll
            for (int j = 0; j < 4; j++) acc_s[i][j] = z4;
#pragma unroll
        for (int jt = 0; jt < 4; jt++) {
            const s16x8 bk0 =
                *(const s16x8*)(Ks + (jt * 16 + lrow) * KSTR + quad * 8);
            const s16x8 bk1 =
                *(const s16x8*)(Ks + (jt * 16 + lrow) * KSTR + 32 + quad * 8);
#pragma unroll
            for (int rowt = 0; rowt < 2; rowt++) {
                acc_s[rowt][jt] = __builtin_amdgcn_mfma_f32_16x16x32_bf16(
                    aq[rowt][0], bk0, acc_s[rowt][jt], 0, 0, 0);
                acc_s[rowt][jt] = __builtin_amdgcn_mfma_f32_16x16x32_bf16(
                    aq[rowt][1], bk1, acc_s[rowt][jt], 0, 0, 0);
            }
        }
        // scale + column mask
        const f32x4 ninf = {-1e30f, -1e30f, -1e30f, -1e30f};
#pragma unroll
        for (int jt = 0; jt < 4; jt++) {
            const bool valid = (j0 + jt * 16 + lrow) < NTOK;
#pragma unroll
            for (int rowt = 0; rowt < 2; rowt++)
                acc_s[rowt][jt] = valid ? acc_s[rowt][jt] * 0.125f : ninf;
        }

        // online softmax + P -> LDS (bf16) + O rescale
#pragma unroll
        for (int rowt = 0; rowt < 2; rowt++) {
#pragma unroll
            for (int rg = 0; rg < 4; rg++) {
                float mx = fmaxf(fmaxf(acc_s[rowt][0][rg], acc_s[rowt][1][rg]),
                                 fmaxf(acc_s[rowt][2][rg], acc_s[rowt][3][rg]));
                mx = fmaxf(mx, __shfl_xor(mx, 1, 64));
                mx = fmaxf(mx, __shfl_xor(mx, 2, 64));
                mx = fmaxf(mx, __shfl_xor(mx, 4, 64));
                mx = fmaxf(mx, __shfl_xor(mx, 8, 64));
                const float nm = fmaxf(m_r[rowt][rg], mx);
                const float al = __expf(m_r[rowt][rg] - nm);
                m_r[rowt][rg] = nm;
                u16* prow = Ps + (size_t)(w * 32 + rowt * 16 + quad * 4 + rg) * KSTR
                            + lrow;
                float ps = 0.f;
#pragma unroll
                for (int jt = 0; jt < 4; jt++) {
                    const float p = __expf(acc_s[rowt][jt][rg] - nm);
                    ps += p;
                    prow[jt * 16] = f2b(p);
                }
                ps += __shfl_xor(ps, 1, 64);
                ps += __shfl_xor(ps, 2, 64);
                ps += __shfl_xor(ps, 4, 64);
                ps += __shfl_xor(ps, 8, 64);
                l_r[rowt][rg] = l_r[rowt][rg] * al + ps;
#pragma unroll
                for (int dt = 0; dt < 4; dt++) acc_o[rowt][dt][rg] *= al;
            }
        }
        // (Ps is per-wave: within-wave LDS ordering suffices, no barrier)

        // O += P V
#pragma unroll
        for (int jc = 0; jc < 2; jc++) {
            const s16x8 ap0 = *(const s16x8*)(
                Ps + (w * 32 + lrow) * KSTR + jc * 32 + quad * 8);
            const s16x8 ap1 = *(const s16x8*)(
                Ps + (w * 32 + 16 + lrow) * KSTR + jc * 32 + quad * 8);
#pragma unroll
            for (int dt = 0; dt < 4; dt++) {
                const s16x8 bv = *(const s16x8*)(
                    Vt + (dt * 16 + lrow) * KSTR + jc * 32 + quad * 8);
                acc_o[0][dt] = __builtin_amdgcn_mfma_f32_16x16x32_bf16(
                    ap0, bv, acc_o[0][dt], 0, 0, 0);
                acc_o[1][dt] = __builtin_amdgcn_mfma_f32_16x16x32_bf16(
                    ap1, bv, acc_o[1][dt], 0, 0, 0);
            }
        }
    }

    // epilogue: O /= l, store bf16
#pragma unroll
    for (int rowt = 0; rowt < 2; rowt++) {
#pragma unroll
        for (int rg = 0; rg < 4; rg++) {
            const int tok = q0 + w * 32 + rowt * 16 + quad * 4 + rg;
            if (tok >= NTOK) continue;
            const float inv = 1.0f / l_r[rowt][rg];
            u16* dst = out + (tokbase + tok) * D_ + hh * 64 + lrow;
#pragma unroll
            for (int dt = 0; dt < 4; dt++)
                dst[dt * 16] = f2b(acc_o[rowt][dt][rg] * inv);
        }
    }
}

// ---------------- im2col (fp32 -> bf16 patches) ----------------
__global__ __launch_bounds__(256) void im2col_kernel(
    const float* __restrict__ x, u16* __restrict__ patches)
{
    const int idx = blockIdx.x * 256 + threadIdx.x;  // over MPAT*96 8-chunks
    if (idx >= MPAT * 96) return;
    const int prow = idx / 96;
    const int c8 = (idx % 96) * 8;
    const int bb = prow / NPAT;
    const int pp = prow % NPAT;
    const int gy = pp / 28, gx = pp % 28;
    const int c = c8 >> 8;
    const int rem = c8 & 255;
    const int py = rem >> 4, px = rem & 15;
    const float* src =
        x + (((size_t)(bb * 3 + c) * 448 + gy * 16 + py) * 448 + gx * 16 + px);
    const float4 a = *(const float4*)src;
    const float4 bq = *(const float4*)(src + 4);
    u16* dst = patches + (size_t)prow * 768 + c8;
    uint4 w4;
    w4.x = (u32)f2b(a.x) | ((u32)f2b(a.y) << 16);
    w4.y = (u32)f2b(a.z) | ((u32)f2b(a.w) << 16);
    w4.z = (u32)f2b(bq.x) | ((u32)f2b(bq.y) << 16);
    w4.w = (u32)f2b(bq.z) | ((u32)f2b(bq.w) << 16);
    *(uint4*)dst = w4;
}

// ---------------- assemble h = [cls|conv_out] + pos (fp32) ----------------
__global__ __launch_bounds__(256) void assemble_kernel(
    const float* __restrict__ conv_out, const float* __restrict__ cls,
    const float* __restrict__ pos, float* __restrict__ h)
{
    const int idx = blockIdx.x * 256 + threadIdx.x;  // over MTOT*192 float4s
    if (idx >= MTOT * 192) return;
    const int row = idx / 192;
    const int d = (idx % 192) * 4;
    const int bb = row / NTOK, n = row % NTOK;
    const float4 pv = *(const float4*)(pos + (size_t)n * 768 + d);
    float4 v;
    if (n == 0) {
        const float4 cv = *(const float4*)(cls + d);
        v = make_float4(cv.x + pv.x, cv.y + pv.y, cv.z + pv.z, cv.w + pv.w);
    } else {
        const float4 co =
            *(const float4*)(conv_out + (size_t)(bb * NPAT + n - 1) * 768 + d);
        v = make_float4(co.x + pv.x, co.y + pv.y, co.z + pv.z, co.w + pv.w);
    }
    *(float4*)(h + (size_t)row * 768 + d) = v;
}

// ---------------- host orchestration ----------------
extern "C" void kernel_launch(void* const* d_in, const int* in_sizes, int n_in,
                              void* d_out, int out_size, void* d_ws, size_t ws_size,
                              hipStream_t stream)
{
    const float* x      = (const float*)d_in[0];
    const float* conv_w = (const float*)d_in[1];
    const float* conv_b = (const float*)d_in[2];
    const float* cls    = (const float*)d_in[3];
    const float* pos    = (const float*)d_in[4];
    const float* ln1_g  = (const float*)d_in[5];
    const float* ln1_b  = (const float*)d_in[6];
    const float* qkv_w  = (const float*)d_in[7];
    const float* qkv_b  = (const float*)d_in[8];
    const float* proj_w = (const float*)d_in[9];
    const float* proj_b = (const float*)d_in[10];
    const float* ln2_g  = (const float*)d_in[11];
    const float* ln2_b  = (const float*)d_in[12];
    const float* w1     = (const float*)d_in[13];
    const float* b1     = (const float*)d_in[14];
    const float* w2     = (const float*)d_in[15];
    const float* b2     = (const float*)d_in[16];
    const float* lnf_g  = (const float*)d_in[17];
    const float* lnf_b  = (const float*)d_in[18];
    float* out = (float*)d_out;

    char* p = (char*)d_ws;
    auto alloc = [&](size_t bytes) {
        char* r = p;
        p += (bytes + 255) & ~(size_t)255;
        return r;
    };
    float* h    = (float*)alloc((size_t)MPAD * 768 * 4);
    u16*  y     = (u16*)alloc((size_t)MPAD * 768 * 2);
    u16*  qkv   = (u16*)alloc((size_t)MPAD * 2304 * 2);
    u16*  attn  = (u16*)alloc((size_t)MPAD * 768 * 2);
    u16*  mid   = (u16*)alloc((size_t)MPAD * 3072 * 2);
    u16*  wq    = (u16*)alloc((size_t)2304 * 768 * 2);
    u16*  wp    = (u16*)alloc((size_t)768 * 768 * 2);
    u16*  w1t   = (u16*)alloc((size_t)3072 * 768 * 2);
    u16*  w2t   = (u16*)alloc((size_t)768 * 3072 * 2);
    u16*  wcv   = (u16*)alloc((size_t)768 * 768 * 2);
    (void)alloc(4096);
    u16*   patches = mid;          // pre-loop alias
    float* cbuf    = (float*)qkv;  // pre-loop alias (fp32 conv out)

    const dim3 blk(256);

    flatcvt_kernel<<<(768 * 768 / 4 + 255) / 256, blk, 0, stream>>>(conv_w, wcv,
                                                                    768 * 768 / 4);
    im2col_kernel<<<(MPAT * 96 + 255) / 256, blk, 0, stream>>>(x, patches);
    mfma_gemm<0, 0><<<dim3(6, MPAT / 128), blk, 0, stream>>>(
        patches, wcv, conv_b, nullptr, cbuf, MPAT, 768, 768);
    assemble_kernel<<<(MTOT * 192 + 255) / 256, blk, 0, stream>>>(cbuf, cls, pos, h);

    for (int l = 0; l < L_; l++) {
        wt_kernel<<<dim3(2304 / 32, 768 / 32), blk, 0, stream>>>(
            qkv_w + (size_t)l * 768 * 2304, wq, 768, 2304);
        wt_kernel<<<dim3(768 / 32, 768 / 32), blk, 0, stream>>>(
            proj_w + (size_t)l * 768 * 768, wp, 768, 768);
        wt_kernel<<<dim3(3072 / 32, 768 / 32), blk, 0, stream>>>(
            w1 + (size_t)l * 768 * 3072, w1t, 768, 3072);
        wt_kernel<<<dim3(768 / 32, 3072 / 32), blk, 0, stream>>>(
            w2 + (size_t)l * 3072 * 768, w2t, 3072, 768);

        ln_kernel<1><<<MTOT, blk, 0, stream>>>(h, ln1_g + l * 768, ln1_b + l * 768,
                                               y, 768);
        mfma_gemm<0, 1><<<dim3(18, 50), blk, 0, stream>>>(
            y, wq, qkv_b + l * 2304, nullptr, qkv, MTOT, 2304, 768);
        attn_kernel<<<dim3((NTOK + AQB - 1) / AQB, B_ * H_), blk, 0, stream>>>(
            qkv, attn);
        mfma_gemm<2, 0><<<dim3(6, 50), blk, 0, stream>>>(
            attn, wp, proj_b + l * 768, h, h, MTOT, 768, 768);
        ln_kernel<1><<<MTOT, blk, 0, stream>>>(h, ln2_g + l * 768, ln2_b + l * 768,
                                               y, 768);
        mfma_gemm<1, 1><<<dim3(24, 50), blk, 0, stream>>>(
            y, w1t, b1 + l * DFF, nullptr, mid, MTOT, DFF, 768);
        mfma_gemm<2, 0><<<dim3(6, 50), blk, 0, stream>>>(
            mid, w2t, b2 + l * 768, h, h, MTOT, 768, DFF);
    }

    ln_kernel<0><<<B_, blk, 0, stream>>>(h, lnf_g, lnf_b, out, (size_t)NTOK * 768);
}